// Round 7
// baseline (253.120 us; speedup 1.0000x reference)
//
#include <hip/hip_runtime.h>
#include <math.h>

#define B_  4
#define S_  2048
#define H_  768
#define NH_ 12
#define HD_ 64
#define M_  (B_*S_)   // 8192
#define K_  768
#define LOG2E 1.44269504088896340736f

using bf16x8 = __attribute__((ext_vector_type(8))) short;
using s16x4  = __attribute__((ext_vector_type(4))) short;
using f32x4  = __attribute__((ext_vector_type(4))) float;

__device__ inline short f2bf(float f) {
    union { float f; unsigned u; } v{f};
    unsigned r = (v.u + 0x7FFF + ((v.u >> 16) & 1)) >> 16;   // RNE
    return (short)r;
}

__device__ inline unsigned cvt_pk_bf16(float lo, float hi) {
    unsigned r;
    asm("v_cvt_pk_bf16_f32 %0, %1, %2" : "=v"(r) : "v"(lo), "v"(hi));
    return r;
}

#define GLDS16(g, l) __builtin_amdgcn_global_load_lds( \
    (const __attribute__((address_space(1))) void*)(g), \
    (__attribute__((address_space(3))) void*)(l), 16, 0, 0)

// swizzled LDS read: linear [R][128B] tile, byte ^= ((row&7)<<4)
__device__ inline const bf16x8* LDSRD(const short* base, int row, int colByte) {
    return (const bf16x8*)((const char*)base + ((row << 7) + (colByte ^ ((row & 7) << 4))));
}

// ---------------------------------------------------------------------------
// fp32 -> bf16 conversion: region per blockIdx.y (hs, Wq, Wk, Wv, Wo)
// ---------------------------------------------------------------------------
__global__ __launch_bounds__(256)
void cvt5(const float* __restrict__ s0, const float* __restrict__ s1,
          const float* __restrict__ s2, const float* __restrict__ s3,
          const float* __restrict__ s4,
          short* __restrict__ d0, short* __restrict__ d1,
          short* __restrict__ d2, short* __restrict__ d3,
          short* __restrict__ d4) {
    const int r = blockIdx.y;
    const float* s = r == 0 ? s0 : r == 1 ? s1 : r == 2 ? s2 : r == 3 ? s3 : s4;
    short* d      = r == 0 ? d0 : r == 1 ? d1 : r == 2 ? d2 : r == 3 ? d3 : d4;
    const int n4  = (r == 0 ? M_ * H_ : H_ * H_) >> 2;
    for (int i = blockIdx.x * blockDim.x + threadIdx.x; i < n4; i += gridDim.x * blockDim.x) {
        float4 v = ((const float4*)s)[i];
        s16x4 o;
        o[0] = f2bf(v.x); o[1] = f2bf(v.y); o[2] = f2bf(v.z); o[3] = f2bf(v.w);
        ((s16x4*)d)[i] = o;
    }
}

// mask * log2e (fp32, tiny)
__global__ __launch_bounds__(256)
void scale_mask(const float* __restrict__ m, float* __restrict__ o) {
    const int i = blockIdx.x * 256 + threadIdx.x;
    if (i < B_ * S_) o[i] = m[i] * LOG2E;
}

// ---------------------------------------------------------------------------
// bf16 MFMA GEMM (m97 structure): 128x128 tile, BK=32, global_load_lds.
// MODE 0: out bf16 head-major [b][h][s][d], val=(acc+bias)*scale  (QKV)
// MODE 1: out fp32 [m][768],  val= acc+bias+res                    (O-proj)
// ---------------------------------------------------------------------------
template<int MODE>
__global__ __launch_bounds__(256)
void gemm_bf16(const short* __restrict__ A, const short* __restrict__ Bw,
               const float* __restrict__ bias, const float* __restrict__ res,
               void* __restrict__ out, float scale) {
    __shared__ __align__(16) short As[128 * 32];
    __shared__ __align__(16) short Bs[128 * 32];
    const int tid = threadIdx.x;
    const int w = tid >> 6, l = tid & 63;
    const int l16 = l & 15, lg = l >> 4;
    const int wm = w >> 1, wn = w & 1;
    const int m0 = blockIdx.x * 128, n0 = blockIdx.y * 128;

    f32x4 acc[4][4];
    #pragma unroll
    for (int mi = 0; mi < 4; mi++)
        #pragma unroll
        for (int ni = 0; ni < 4; ni++)
            acc[mi][ni][0] = acc[mi][ni][1] = acc[mi][ni][2] = acc[mi][ni][3] = 0.f;

    for (int k0 = 0; k0 < K_; k0 += 32) {
        #pragma unroll
        for (int i = 0; i < 2; i++) {
            const int o = w * 2048 + i * 1024 + l * 16;
            const int row = o >> 6, colb = o & 63;
            const char* ga = (const char*)A  + (((size_t)(m0 + row)) * K_ + k0) * 2 + colb;
            const char* gb = (const char*)Bw + (((size_t)(n0 + row)) * K_ + k0) * 2 + colb;
            GLDS16(ga, (char*)As + w * 2048 + i * 1024);
            GLDS16(gb, (char*)Bs + w * 2048 + i * 1024);
        }
        __syncthreads();

        bf16x8 af[4], bfr[4];
        #pragma unroll
        for (int mi = 0; mi < 4; mi++)
            af[mi] = *(const bf16x8*)&As[(wm * 64 + mi * 16 + l16) * 32 + lg * 8];
        #pragma unroll
        for (int ni = 0; ni < 4; ni++)
            bfr[ni] = *(const bf16x8*)&Bs[(wn * 64 + ni * 16 + l16) * 32 + lg * 8];
        #pragma unroll
        for (int mi = 0; mi < 4; mi++)
            #pragma unroll
            for (int ni = 0; ni < 4; ni++)
                acc[mi][ni] = __builtin_amdgcn_mfma_f32_16x16x32_bf16(af[mi], bfr[ni], acc[mi][ni], 0, 0, 0);
        __syncthreads();
    }

    float bcol[4];
    #pragma unroll
    for (int ni = 0; ni < 4; ni++) bcol[ni] = bias[n0 + wn * 64 + ni * 16 + l16];

    if (MODE == 0) {
        short* obf = (short*)out;
        const int h = blockIdx.y * 2 + wn;
        #pragma unroll
        for (int mi = 0; mi < 4; mi++) {
            #pragma unroll
            for (int r = 0; r < 4; r++) {
                const int row = m0 + wm * 64 + mi * 16 + lg * 4 + r;
                const int bb = row >> 11, ss = row & 2047;
                const size_t base = (((size_t)(bb * NH_ + h)) * S_ + ss) * HD_;
                #pragma unroll
                for (int ni = 0; ni < 4; ni++)
                    obf[base + ni * 16 + l16] = f2bf((acc[mi][ni][r] + bcol[ni]) * scale);
            }
        }
    } else {
        float* o = (float*)out;
        #pragma unroll
        for (int mi = 0; mi < 4; mi++) {
            #pragma unroll
            for (int r = 0; r < 4; r++) {
                const int row = m0 + wm * 64 + mi * 16 + lg * 4 + r;
                #pragma unroll
                for (int ni = 0; ni < 4; ni++) {
                    const int col = n0 + wn * 64 + ni * 16 + l16;
                    o[(size_t)row * H_ + col] = acc[mi][ni][r] + bcol[ni] + res[(size_t)row * H_ + col];
                }
            }
        }
    }
}

// ---------------------------------------------------------------------------
// V transpose: [b][h][s][d] -> [b][h][d][s].  64x64 LDS tiles, XOR-swizzled.
// ---------------------------------------------------------------------------
__global__ __launch_bounds__(256)
void transpose_v(const short* __restrict__ vin, short* __restrict__ vout) {
    __shared__ __align__(16) short L[4096];
    const int bh = blockIdx.y, st = blockIdx.x * 64;
    const int t = threadIdx.x;
    const int sl = t >> 2, d0 = (t & 3) * 16;
    const short* g = vin + ((size_t)bh * S_ + st + sl) * HD_ + d0;
    #pragma unroll
    for (int u = 0; u < 2; u++) {
        const int cb = (d0 + u * 8) * 2;
        *(bf16x8*)((char*)L + (sl << 7) + (cb ^ ((sl & 7) << 4))) = *(const bf16x8*)(g + u * 8);
    }
    __syncthreads();
    const int d = t >> 2, s0 = (t & 3) * 16;
    short tmp[16];
    #pragma unroll
    for (int j = 0; j < 16; j++) {
        const int row = s0 + j;
        tmp[j] = *(const short*)((const char*)L + (row << 7) + ((d * 2) ^ ((row & 7) << 4)));
    }
    short* o = vout + ((size_t)bh * HD_ + d) * S_ + st + s0;
    *(bf16x8*)(o)     = *(bf16x8*)&tmp[0];
    *(bf16x8*)(o + 8) = *(bf16x8*)&tmp[8];
}

// ---------------------------------------------------------------------------
// online-softmax + P-store for one 16-q-row subset (lane-local, exp2 domain)
// ---------------------------------------------------------------------------
__device__ inline void softmax_store(f32x4 (&sacc)[4], float& m_reg, float& l_reg,
                                     f32x4 (&oacc)[4], short* PsL, int prow, int lg) {
    float x0 = fmaxf(fmaxf(sacc[0][0], sacc[0][1]), fmaxf(sacc[0][2], sacc[0][3]));
    float x1 = fmaxf(fmaxf(sacc[1][0], sacc[1][1]), fmaxf(sacc[1][2], sacc[1][3]));
    float x2 = fmaxf(fmaxf(sacc[2][0], sacc[2][1]), fmaxf(sacc[2][2], sacc[2][3]));
    float x3 = fmaxf(fmaxf(sacc[3][0], sacc[3][1]), fmaxf(sacc[3][2], sacc[3][3]));
    float pmax = fmaxf(fmaxf(x0, x1), fmaxf(x2, x3));
    pmax = fmaxf(pmax, __shfl_xor(pmax, 16));
    pmax = fmaxf(pmax, __shfl_xor(pmax, 32));

    if (!__all(pmax - m_reg <= 8.f)) {       // defer-max (T13), log2 units
        const float mn = fmaxf(m_reg, pmax);
        const float corr = __builtin_amdgcn_exp2f(m_reg - mn);
        l_reg *= corr;
        m_reg = mn;
        float corr4[4];
        #pragma unroll
        for (int r = 0; r < 4; r++) corr4[r] = __shfl(corr, lg * 4 + r);
        #pragma unroll
        for (int nd = 0; nd < 4; nd++)
            #pragma unroll
            for (int r = 0; r < 4; r++) oacc[nd][r] *= corr4[r];
    }

    float rs = 0.f;
    #pragma unroll
    for (int n = 0; n < 4; n++)
        #pragma unroll
        for (int r = 0; r < 4; r++) {
            sacc[n][r] = __builtin_amdgcn_exp2f(sacc[n][r] - m_reg);
            rs += sacc[n][r];
        }
    rs += __shfl_xor(rs, 16);
    rs += __shfl_xor(rs, 32);
    l_reg += rs;

    #pragma unroll
    for (int n = 0; n < 4; n++) {
        uint2 pk;
        pk.x = cvt_pk_bf16(sacc[n][0], sacc[n][1]);
        pk.y = cvt_pk_bf16(sacc[n][2], sacc[n][3]);
        *(uint2*)((char*)PsL + (prow << 7) + ((32 * n + 8 * lg) ^ ((prow & 7) << 4))) = pk;
    }
}

// ---------------------------------------------------------------------------
// MFMA flash attention: Q-block 128 (4 waves x 32 q-rows), KV tile 64,
// double-buffered K/Vt via global_load_lds, ONE barrier per tile with
// prefetch issued before compute (T3 minimum-2-phase).  exp2 softmax,
// defer-max, cvt_pk P-pack.  Q pre-scaled 0.125*log2e; mask pre-scaled.
// ---------------------------------------------------------------------------
__global__ __launch_bounds__(256)
void flash_attn_mfma(const short* __restrict__ q, const short* __restrict__ k,
                     const short* __restrict__ vt, const float* __restrict__ mask,
                     short* __restrict__ ctx) {
    const int qt = blockIdx.x, h = blockIdx.y, b = blockIdx.z;
    __shared__ __align__(16) short KsL[2][4096];   // [buf][64 rows][128B] swz
    __shared__ __align__(16) short VtL[2][4096];   // [buf][64 d   ][128B] swz
    __shared__ __align__(16) short PsL[8192];      // [128 q-rows ][128B] swz
    const int tid = threadIdx.x;
    const int w = tid >> 6, l = tid & 63;
    const int l16 = l & 15, lg = l >> 4;

    const size_t bh = (size_t)(b * NH_ + h);
    // Q fragments: subset a = q-rows qt*128 + w*32 + (0..15), subset b = +16
    const size_t qra = (bh * S_ + qt * 128 + w * 32 + l16) * HD_;
    bf16x8 qfa0 = *(const bf16x8*)(q + qra + lg * 8);
    bf16x8 qfa1 = *(const bf16x8*)(q + qra + 32 + lg * 8);
    bf16x8 qfb0 = *(const bf16x8*)(q + qra + 16 * HD_ + lg * 8);
    bf16x8 qfb1 = *(const bf16x8*)(q + qra + 16 * HD_ + 32 + lg * 8);

    const size_t kbase  = bh * S_ * HD_;   // K  [s][d]
    const size_t vtbase = bh * HD_ * S_;   // Vt [d][s]

    f32x4 oa[4], ob[4];
    #pragma unroll
    for (int i = 0; i < 4; i++) {
        oa[i][0] = oa[i][1] = oa[i][2] = oa[i][3] = 0.f;
        ob[i][0] = ob[i][1] = ob[i][2] = ob[i][3] = 0.f;
    }
    float m_a = -3.0e38f, l_a = 0.f, m_b = -3.0e38f, l_b = 0.f;

    // stage tile ct into buffer `bu` (4 glds/wave: 2 K + 2 Vt)
    #define STAGE(bu, ct_) do {                                                   \
        _Pragma("unroll")                                                         \
        for (int i_ = 0; i_ < 2; i_++) {                                          \
            const int o_ = (w * 2 + i_) * 1024 + l * 16;                          \
            const int row_ = o_ >> 7;                                             \
            const int cb_ = (o_ & 127) ^ ((row_ & 7) << 4);                       \
            const char* gk_ = (const char*)(k  + kbase  + (size_t)((ct_) * 64 + row_) * HD_) + cb_; \
            const char* gv_ = (const char*)(vt + vtbase + (size_t)row_ * S_ + (ct_) * 64) + cb_;    \
            GLDS16(gk_, (char*)KsL[bu] + o_);                                     \
            GLDS16(gv_, (char*)VtL[bu] + o_);                                     \
        }                                                                         \
    } while (0)

    STAGE(0, 0);
    __syncthreads();

    int cb = 0;
    for (int ct = 0; ct < S_ / 64; ct++) {
        if (ct + 1 < S_ / 64) STAGE(cb ^ 1, ct + 1);   // prefetch under compute

        // ---- K fragments (shared by both q-subsets) ----
        bf16x8 kb0[4], kb1[4];
        #pragma unroll
        for (int n = 0; n < 4; n++) {
            kb0[n] = *LDSRD(KsL[cb], n * 16 + l16, lg * 16);
            kb1[n] = *LDSRD(KsL[cb], n * 16 + l16, 64 + lg * 16);
        }

        // ---- S^T = mfma(K, Q) for both subsets ----
        f32x4 sa[4], sb[4];
        #pragma unroll
        for (int n = 0; n < 4; n++) {
            sa[n][0] = sa[n][1] = sa[n][2] = sa[n][3] = 0.f;
            sb[n][0] = sb[n][1] = sb[n][2] = sb[n][3] = 0.f;
            sa[n] = __builtin_amdgcn_mfma_f32_16x16x32_bf16(kb0[n], qfa0, sa[n], 0, 0, 0);
            sa[n] = __builtin_amdgcn_mfma_f32_16x16x32_bf16(kb1[n], qfa1, sa[n], 0, 0, 0);
            sb[n] = __builtin_amdgcn_mfma_f32_16x16x32_bf16(kb0[n], qfb0, sb[n], 0, 0, 0);
            sb[n] = __builtin_amdgcn_mfma_f32_16x16x32_bf16(kb1[n], qfb1, sb[n], 0, 0, 0);
        }

        // ---- mask (log2-scaled; per kc = 16n+4lg+r, same for both subsets) ----
        #pragma unroll
        for (int n = 0; n < 4; n++) {
            float4 mk = *(const float4*)(mask + (size_t)b * S_ + ct * 64 + n * 16 + lg * 4);
            sa[n][0] += mk.x; sa[n][1] += mk.y; sa[n][2] += mk.z; sa[n][3] += mk.w;
            sb[n][0] += mk.x; sb[n][1] += mk.y; sb[n][2] += mk.z; sb[n][3] += mk.w;
        }

        // ---- softmax + P store (per-wave-private PsL rows; no barrier) ----
        const int pra = w * 32 + l16;
        softmax_store(sa, m_a, l_a, oa, PsL, pra, lg);
        softmax_store(sb, m_b, l_b, ob, PsL, pra + 16, lg);

        // ---- O += P V (V fragments shared by both subsets) ----
        bf16x8 paa0 = *LDSRD(PsL, pra, lg * 16);
        bf16x8 paa1 = *LDSRD(PsL, pra, 64 + lg * 16);
        bf16x8 pab0 = *LDSRD(PsL, pra + 16, lg * 16);
        bf16x8 pab1 = *LDSRD(PsL, pra + 16, 64 + lg * 16);
        #pragma unroll
        for (int nd = 0; nd < 4; nd++) {
            bf16x8 vb0 = *LDSRD(VtL[cb], nd * 16 + l16, lg * 16);
            bf16x8 vb1 = *LDSRD(VtL[cb], nd * 16 + l16, 64 + lg * 16);
            oa[nd] = __builtin_amdgcn_mfma_f32_16x16x32_bf16(paa0, vb0, oa[nd], 0, 0, 0);
            oa[nd] = __builtin_amdgcn_mfma_f32_16x16x32_bf16(paa1, vb1, oa[nd], 0, 0, 0);
            ob[nd] = __builtin_amdgcn_mfma_f32_16x16x32_bf16(pab0, vb0, ob[nd], 0, 0, 0);
            ob[nd] = __builtin_amdgcn_mfma_f32_16x16x32_bf16(pab1, vb1, ob[nd], 0, 0, 0);
        }

        __syncthreads();   // drains prefetch (hidden) + publishes next buffer
        cb ^= 1;
    }
    #undef STAGE

    // ---- normalize + write ctx bf16 [M][H] ----
    #pragma unroll
    for (int r = 0; r < 4; r++) {
        const float inva = 1.f / __shfl(l_a, lg * 4 + r);
        const float invb = 1.f / __shfl(l_b, lg * 4 + r);
        const size_t rowa = (size_t)(b * S_ + qt * 128 + w * 32 + lg * 4 + r);
        #pragma unroll
        for (int nd = 0; nd < 4; nd++) {
            ctx[rowa * H_ + h * HD_ + nd * 16 + l16] = f2bf(oa[nd][r] * inva);
            ctx[(rowa + 16) * H_ + h * HD_ + nd * 16 + l16] = f2bf(ob[nd][r] * invb);
        }
    }
}

// ---------------------------------------------------------------------------
// LayerNorm over last dim (768). One block (256 thr) per row.
// ---------------------------------------------------------------------------
__global__ __launch_bounds__(256)
void layernorm_k(const float* __restrict__ hin, const float* __restrict__ g,
                 const float* __restrict__ beta, float* __restrict__ out) {
    const int row = blockIdx.x;
    const int tid = threadIdx.x;
    const float* x = hin + (size_t)row * H_;
    __shared__ float sm[4];

    float v0 = x[tid], v1 = x[tid + 256], v2 = x[tid + 512];
    float s = v0 + v1 + v2;
    #pragma unroll
    for (int o = 32; o > 0; o >>= 1) s += __shfl_xor(s, o);
    if ((tid & 63) == 0) sm[tid >> 6] = s;
    __syncthreads();
    float mu = (sm[0] + sm[1] + sm[2] + sm[3]) * (1.f / 768.f);

    float d0 = v0 - mu, d1 = v1 - mu, d2 = v2 - mu;
    float ss = d0*d0 + d1*d1 + d2*d2;
    #pragma unroll
    for (int o = 32; o > 0; o >>= 1) ss += __shfl_xor(ss, o);
    __syncthreads();
    if ((tid & 63) == 0) sm[tid >> 6] = ss;
    __syncthreads();
    float var = (sm[0] + sm[1] + sm[2] + sm[3]) * (1.f / 768.f);
    float sc = rsqrtf(var + 1e-12f);

    float* y = out + (size_t)row * H_;
    y[tid]       = d0 * sc * g[tid]       + beta[tid];
    y[tid + 256] = d1 * sc * g[tid + 256] + beta[tid + 256];
    y[tid + 512] = d2 * sc * g[tid + 512] + beta[tid + 512];
}

// ---------------------------------------------------------------------------
extern "C" void kernel_launch(void* const* d_in, const int* in_sizes, int n_in,
                              void* d_out, int out_size, void* d_ws, size_t ws_size,
                              hipStream_t stream) {
    const float* hs   = (const float*)d_in[0];
    const float* mask = (const float*)d_in[1];
    const float* Wq   = (const float*)d_in[2];
    const float* bq   = (const float*)d_in[3];
    const float* Wk   = (const float*)d_in[4];
    const float* bk   = (const float*)d_in[5];
    const float* Wv   = (const float*)d_in[6];
    const float* bv   = (const float*)d_in[7];
    const float* Wo   = (const float*)d_in[8];
    const float* bo   = (const float*)d_in[9];
    const float* ln_g = (const float*)d_in[10];
    const float* ln_b = (const float*)d_in[11];
    float* out = (float*)d_out;

    const size_t MH = (size_t)M_ * H_;
    const size_t HH = (size_t)H_ * H_;
    short* hsbf = (short*)d_ws;       // [M][768] bf16
    short* wqbf = hsbf + MH;
    short* wkbf = wqbf + HH;
    short* wvbf = wkbf + HH;
    short* wobf = wvbf + HH;
    short* qbf  = wobf + HH;          // [b][h][s][d]
    short* kbf  = qbf + MH;
    short* vbf  = kbf + MH;           // [b][h][s][d]
    short* vtb  = vbf + MH;           // [b][h][d][s]
    short* cbf  = vtb + MH;           // ctx bf16 [M][768]
    float* hb   = (float*)(cbf + MH); // fp32 [M][768]
    float* msk2 = hb + MH;            // mask * log2e (8192 fp32)

    cvt5<<<dim3(256, 5), 256, 0, stream>>>(hs, Wq, Wk, Wv, Wo,
                                           hsbf, wqbf, wkbf, wvbf, wobf);
    scale_mask<<<(B_ * S_ + 255) / 256, 256, 0, stream>>>(mask, msk2);

    dim3 gg(M_ / 128, H_ / 128);   // 64 x 6
    gemm_bf16<0><<<gg, 256, 0, stream>>>(hsbf, wqbf, bq, nullptr, qbf, 0.125f * LOG2E);
    gemm_bf16<0><<<gg, 256, 0, stream>>>(hsbf, wkbf, bk, nullptr, kbf, 1.0f);
    gemm_bf16<0><<<gg, 256, 0, stream>>>(hsbf, wvbf, bv, nullptr, vbf, 1.0f);

    transpose_v<<<dim3(S_ / 64, B_ * NH_), 256, 0, stream>>>(vbf, vtb);

    flash_attn_mfma<<<dim3(S_ / 128, NH_, B_), 256, 0, stream>>>(qbf, kbf, vtb, msk2, cbf);

    gemm_bf16<1><<<gg, 256, 0, stream>>>(cbf, wobf, bo, hs, hb, 1.0f);

    layernorm_k<<<M_, 256, 0, stream>>>(hb, ln_g, ln_b, out);
}

// Round 8
// 202.366 us; speedup vs baseline: 1.2508x; 1.2508x over previous
//
#include <hip/hip_runtime.h>
#include <math.h>

#define B_  4
#define S_  2048
#define H_  768
#define NH_ 12
#define HD_ 64
#define M_  (B_*S_)   // 8192
#define K_  768
#define LOG2E 1.44269504088896340736f

using bf16x8 = __attribute__((ext_vector_type(8))) short;
using s16x4  = __attribute__((ext_vector_type(4))) short;
using f32x4  = __attribute__((ext_vector_type(4))) float;

__device__ inline short f2bf(float f) {
    union { float f; unsigned u; } v{f};
    unsigned r = (v.u + 0x7FFF + ((v.u >> 16) & 1)) >> 16;   // RNE
    return (short)r;
}

__device__ inline unsigned cvt_pk_bf16(float lo, float hi) {
    unsigned r;
    asm("v_cvt_pk_bf16_f32 %0, %1, %2" : "=v"(r) : "v"(lo), "v"(hi));
    return r;
}

#define GLDS16(g, l) __builtin_amdgcn_global_load_lds( \
    (const __attribute__((address_space(1))) void*)(g), \
    (__attribute__((address_space(3))) void*)(l), 16, 0, 0)

// swizzled LDS read: linear [R][128B] tile, byte ^= ((row&7)<<4)
__device__ inline const bf16x8* LDSRD(const short* base, int row, int colByte) {
    return (const bf16x8*)((const char*)base + ((row << 7) + (colByte ^ ((row & 7) << 4))));
}

// ---------------------------------------------------------------------------
// fp32 -> bf16 conversion: region per blockIdx.y (hs, Wq, Wk, Wv, Wo)
// ---------------------------------------------------------------------------
__global__ __launch_bounds__(256)
void cvt5(const float* __restrict__ s0, const float* __restrict__ s1,
          const float* __restrict__ s2, const float* __restrict__ s3,
          const float* __restrict__ s4,
          short* __restrict__ d0, short* __restrict__ d1,
          short* __restrict__ d2, short* __restrict__ d3,
          short* __restrict__ d4) {
    const int r = blockIdx.y;
    const float* s = r == 0 ? s0 : r == 1 ? s1 : r == 2 ? s2 : r == 3 ? s3 : s4;
    short* d      = r == 0 ? d0 : r == 1 ? d1 : r == 2 ? d2 : r == 3 ? d3 : d4;
    const int n4  = (r == 0 ? M_ * H_ : H_ * H_) >> 2;
    for (int i = blockIdx.x * blockDim.x + threadIdx.x; i < n4; i += gridDim.x * blockDim.x) {
        float4 v = ((const float4*)s)[i];
        s16x4 o;
        o[0] = f2bf(v.x); o[1] = f2bf(v.y); o[2] = f2bf(v.z); o[3] = f2bf(v.w);
        ((s16x4*)d)[i] = o;
    }
}

// mask * log2e (fp32, tiny)
__global__ __launch_bounds__(256)
void scale_mask(const float* __restrict__ m, float* __restrict__ o) {
    const int i = blockIdx.x * 256 + threadIdx.x;
    if (i < B_ * S_) o[i] = m[i] * LOG2E;
}

// ---------------------------------------------------------------------------
// Fused QKV GEMM: weights stored consecutively as [2304][768] bf16.
// grid (M/128, 18). which = y/6 (0=Q,1=K,2=V); out bf16 head-major.
// ---------------------------------------------------------------------------
__global__ __launch_bounds__(256)
void gemm_qkv(const short* __restrict__ A, const short* __restrict__ Bw,
              const float* __restrict__ bq, const float* __restrict__ bk,
              const float* __restrict__ bv, short* __restrict__ obase) {
    __shared__ __align__(16) short As[128 * 32];
    __shared__ __align__(16) short Bs[128 * 32];
    const int tid = threadIdx.x;
    const int w = tid >> 6, l = tid & 63;
    const int l16 = l & 15, lg = l >> 4;
    const int wm = w >> 1, wn = w & 1;
    const int m0 = blockIdx.x * 128, n0 = blockIdx.y * 128;
    const int which = blockIdx.y / 6;
    const float* bias = which == 0 ? bq : which == 1 ? bk : bv;
    const float scale = which == 0 ? 0.125f * LOG2E : 1.0f;
    short* obf = obase + (size_t)which * M_ * H_;

    f32x4 acc[4][4];
    #pragma unroll
    for (int mi = 0; mi < 4; mi++)
        #pragma unroll
        for (int ni = 0; ni < 4; ni++)
            acc[mi][ni][0] = acc[mi][ni][1] = acc[mi][ni][2] = acc[mi][ni][3] = 0.f;

    for (int k0 = 0; k0 < K_; k0 += 32) {
        #pragma unroll
        for (int i = 0; i < 2; i++) {
            const int o = w * 2048 + i * 1024 + l * 16;
            const int row = o >> 6, colb = o & 63;
            const char* ga = (const char*)A  + (((size_t)(m0 + row)) * K_ + k0) * 2 + colb;
            const char* gb = (const char*)Bw + (((size_t)(n0 + row)) * K_ + k0) * 2 + colb;
            GLDS16(ga, (char*)As + w * 2048 + i * 1024);
            GLDS16(gb, (char*)Bs + w * 2048 + i * 1024);
        }
        __syncthreads();

        bf16x8 af[4], bfr[4];
        #pragma unroll
        for (int mi = 0; mi < 4; mi++)
            af[mi] = *(const bf16x8*)&As[(wm * 64 + mi * 16 + l16) * 32 + lg * 8];
        #pragma unroll
        for (int ni = 0; ni < 4; ni++)
            bfr[ni] = *(const bf16x8*)&Bs[(wn * 64 + ni * 16 + l16) * 32 + lg * 8];
        #pragma unroll
        for (int mi = 0; mi < 4; mi++)
            #pragma unroll
            for (int ni = 0; ni < 4; ni++)
                acc[mi][ni] = __builtin_amdgcn_mfma_f32_16x16x32_bf16(af[mi], bfr[ni], acc[mi][ni], 0, 0, 0);
        __syncthreads();
    }

    const int ncol0 = (blockIdx.y % 6) * 128;
    float bcol[4];
    #pragma unroll
    for (int ni = 0; ni < 4; ni++) bcol[ni] = bias[ncol0 + wn * 64 + ni * 16 + l16];

    const int h = (blockIdx.y % 6) * 2 + wn;
    #pragma unroll
    for (int mi = 0; mi < 4; mi++) {
        #pragma unroll
        for (int r = 0; r < 4; r++) {
            const int row = m0 + wm * 64 + mi * 16 + lg * 4 + r;
            const int bb = row >> 11, ss = row & 2047;
            const size_t base = (((size_t)(bb * NH_ + h)) * S_ + ss) * HD_;
            #pragma unroll
            for (int ni = 0; ni < 4; ni++)
                obf[base + ni * 16 + l16] = f2bf((acc[mi][ni][r] + bcol[ni]) * scale);
        }
    }
}

// ---------------------------------------------------------------------------
// O-proj GEMM: out fp32 = acc + bias + res  (128x128, BK=32, global_load_lds)
// ---------------------------------------------------------------------------
__global__ __launch_bounds__(256)
void gemm_out(const short* __restrict__ A, const short* __restrict__ Bw,
              const float* __restrict__ bias, const float* __restrict__ res,
              float* __restrict__ o) {
    __shared__ __align__(16) short As[128 * 32];
    __shared__ __align__(16) short Bs[128 * 32];
    const int tid = threadIdx.x;
    const int w = tid >> 6, l = tid & 63;
    const int l16 = l & 15, lg = l >> 4;
    const int wm = w >> 1, wn = w & 1;
    const int m0 = blockIdx.x * 128, n0 = blockIdx.y * 128;

    f32x4 acc[4][4];
    #pragma unroll
    for (int mi = 0; mi < 4; mi++)
        #pragma unroll
        for (int ni = 0; ni < 4; ni++)
            acc[mi][ni][0] = acc[mi][ni][1] = acc[mi][ni][2] = acc[mi][ni][3] = 0.f;

    for (int k0 = 0; k0 < K_; k0 += 32) {
        #pragma unroll
        for (int i = 0; i < 2; i++) {
            const int o_ = w * 2048 + i * 1024 + l * 16;
            const int row = o_ >> 6, colb = o_ & 63;
            const char* ga = (const char*)A  + (((size_t)(m0 + row)) * K_ + k0) * 2 + colb;
            const char* gb = (const char*)Bw + (((size_t)(n0 + row)) * K_ + k0) * 2 + colb;
            GLDS16(ga, (char*)As + w * 2048 + i * 1024);
            GLDS16(gb, (char*)Bs + w * 2048 + i * 1024);
        }
        __syncthreads();

        bf16x8 af[4], bfr[4];
        #pragma unroll
        for (int mi = 0; mi < 4; mi++)
            af[mi] = *(const bf16x8*)&As[(wm * 64 + mi * 16 + l16) * 32 + lg * 8];
        #pragma unroll
        for (int ni = 0; ni < 4; ni++)
            bfr[ni] = *(const bf16x8*)&Bs[(wn * 64 + ni * 16 + l16) * 32 + lg * 8];
        #pragma unroll
        for (int mi = 0; mi < 4; mi++)
            #pragma unroll
            for (int ni = 0; ni < 4; ni++)
                acc[mi][ni] = __builtin_amdgcn_mfma_f32_16x16x32_bf16(af[mi], bfr[ni], acc[mi][ni], 0, 0, 0);
        __syncthreads();
    }

    float bcol[4];
    #pragma unroll
    for (int ni = 0; ni < 4; ni++) bcol[ni] = bias[n0 + wn * 64 + ni * 16 + l16];
    #pragma unroll
    for (int mi = 0; mi < 4; mi++) {
        #pragma unroll
        for (int r = 0; r < 4; r++) {
            const int row = m0 + wm * 64 + mi * 16 + lg * 4 + r;
            #pragma unroll
            for (int ni = 0; ni < 4; ni++) {
                const int col = n0 + wn * 64 + ni * 16 + l16;
                o[(size_t)row * H_ + col] = acc[mi][ni][r] + bcol[ni] + res[(size_t)row * H_ + col];
            }
        }
    }
}

// ---------------------------------------------------------------------------
// V transpose: [b][h][s][d] -> [b][h][d][s].  64x64 LDS tiles, XOR-swizzled.
// ---------------------------------------------------------------------------
__global__ __launch_bounds__(256)
void transpose_v(const short* __restrict__ vin, short* __restrict__ vout) {
    __shared__ __align__(16) short L[4096];
    const int bh = blockIdx.y, st = blockIdx.x * 64;
    const int t = threadIdx.x;
    const int sl = t >> 2, d0 = (t & 3) * 16;
    const short* g = vin + ((size_t)bh * S_ + st + sl) * HD_ + d0;
    #pragma unroll
    for (int u = 0; u < 2; u++) {
        const int cb = (d0 + u * 8) * 2;
        *(bf16x8*)((char*)L + (sl << 7) + (cb ^ ((sl & 7) << 4))) = *(const bf16x8*)(g + u * 8);
    }
    __syncthreads();
    const int d = t >> 2, s0 = (t & 3) * 16;
    short tmp[16];
    #pragma unroll
    for (int j = 0; j < 16; j++) {
        const int row = s0 + j;
        tmp[j] = *(const short*)((const char*)L + (row << 7) + ((d * 2) ^ ((row & 7) << 4)));
    }
    short* o = vout + ((size_t)bh * HD_ + d) * S_ + st + s0;
    *(bf16x8*)(o)     = *(bf16x8*)&tmp[0];
    *(bf16x8*)(o + 8) = *(bf16x8*)&tmp[8];
}

// ---------------------------------------------------------------------------
// online-softmax + P-store for one 16-q-row subset (lane-local, exp2 domain)
// ---------------------------------------------------------------------------
__device__ inline void softmax_store(f32x4 (&sacc)[4], float& m_reg, float& l_reg,
                                     f32x4 (&oacc)[4], short* PsL, int prow, int lg) {
    float x0 = fmaxf(fmaxf(sacc[0][0], sacc[0][1]), fmaxf(sacc[0][2], sacc[0][3]));
    float x1 = fmaxf(fmaxf(sacc[1][0], sacc[1][1]), fmaxf(sacc[1][2], sacc[1][3]));
    float x2 = fmaxf(fmaxf(sacc[2][0], sacc[2][1]), fmaxf(sacc[2][2], sacc[2][3]));
    float x3 = fmaxf(fmaxf(sacc[3][0], sacc[3][1]), fmaxf(sacc[3][2], sacc[3][3]));
    float pmax = fmaxf(fmaxf(x0, x1), fmaxf(x2, x3));
    pmax = fmaxf(pmax, __shfl_xor(pmax, 16));
    pmax = fmaxf(pmax, __shfl_xor(pmax, 32));

    if (!__all(pmax - m_reg <= 8.f)) {       // defer-max (T13), log2 units
        const float mn = fmaxf(m_reg, pmax);
        const float corr = __builtin_amdgcn_exp2f(m_reg - mn);
        l_reg *= corr;
        m_reg = mn;
        float corr4[4];
        #pragma unroll
        for (int r = 0; r < 4; r++) corr4[r] = __shfl(corr, lg * 4 + r);
        #pragma unroll
        for (int nd = 0; nd < 4; nd++)
            #pragma unroll
            for (int r = 0; r < 4; r++) oacc[nd][r] *= corr4[r];
    }

    float rs = 0.f;
    #pragma unroll
    for (int n = 0; n < 4; n++)
        #pragma unroll
        for (int r = 0; r < 4; r++) {
            sacc[n][r] = __builtin_amdgcn_exp2f(sacc[n][r] - m_reg);
            rs += sacc[n][r];
        }
    rs += __shfl_xor(rs, 16);
    rs += __shfl_xor(rs, 32);
    l_reg += rs;

    #pragma unroll
    for (int n = 0; n < 4; n++) {
        uint2 pk;
        pk.x = cvt_pk_bf16(sacc[n][0], sacc[n][1]);
        pk.y = cvt_pk_bf16(sacc[n][2], sacc[n][3]);
        *(uint2*)((char*)PsL + (prow << 7) + ((32 * n + 8 * lg) ^ ((prow & 7) << 4))) = pk;
    }
}

// ---------------------------------------------------------------------------
// MFMA flash attention: Q-block 64 (4 waves x 16 q-rows), KV tile 64.
// Async-STAGE split (T14): global->reg loads issued at loop top, reg->LDS
// ds_write at loop bottom into the OTHER buffer, ONE barrier per tile.
// exp2 softmax, defer-max, cvt_pk.  Q pre-scaled 0.125*log2e; mask scaled.
// ---------------------------------------------------------------------------
__global__ __launch_bounds__(256)
void flash_attn_mfma(const short* __restrict__ q, const short* __restrict__ k,
                     const short* __restrict__ vt, const float* __restrict__ mask,
                     short* __restrict__ ctx) {
    const int qt = blockIdx.x, h = blockIdx.y, b = blockIdx.z;
    __shared__ __align__(16) short KsL[2][4096];   // [buf][64 s][128B] swz
    __shared__ __align__(16) short VtL[2][4096];   // [buf][64 d][128B] swz
    __shared__ __align__(16) short PsL[4096];      // [64 q-rows][128B] swz
    const int tid = threadIdx.x;
    const int w = tid >> 6, l = tid & 63;
    const int l16 = l & 15, lg = l >> 4;

    const size_t bh = (size_t)(b * NH_ + h);
    const size_t qrow = (bh * S_ + qt * 64 + w * 16 + l16) * HD_;
    bf16x8 qf0 = *(const bf16x8*)(q + qrow + lg * 8);
    bf16x8 qf1 = *(const bf16x8*)(q + qrow + 32 + lg * 8);

    const size_t kbase  = bh * S_ * HD_;   // K  [s][d]
    const size_t vtbase = bh * HD_ * S_;   // Vt [d][s]

    f32x4 oacc[4];
    #pragma unroll
    for (int i = 0; i < 4; i++) oacc[i][0] = oacc[i][1] = oacc[i][2] = oacc[i][3] = 0.f;
    float m_reg = -3.0e38f, l_reg = 0.f;

    // staging regs: wave w stages rows w*16..w*16+15 of K tile and of Vt tile
    bf16x8 nk[2], nv[2];
    // chunk c = l*2+i: row = w*16 + (c>>3), 16B col = (c&7)
    #define LOADN(ct_) do {                                                       \
        _Pragma("unroll")                                                         \
        for (int i_ = 0; i_ < 2; i_++) {                                          \
            const int c_ = l * 2 + i_;                                            \
            const int row_ = w * 16 + (c_ >> 3);                                  \
            const int cB_ = (c_ & 7) * 16;                                        \
            nk[i_] = *(const bf16x8*)((const char*)(k  + kbase  + (size_t)((ct_) * 64 + row_) * HD_) + cB_); \
            nv[i_] = *(const bf16x8*)((const char*)(vt + vtbase + (size_t)row_ * S_ + (ct_) * 64) + cB_);    \
        }                                                                         \
    } while (0)
    #define WRITEN(bu) do {                                                       \
        _Pragma("unroll")                                                         \
        for (int i_ = 0; i_ < 2; i_++) {                                          \
            const int c_ = l * 2 + i_;                                            \
            const int row_ = w * 16 + (c_ >> 3);                                  \
            const int byte_ = (row_ << 7) + (((c_ & 7) * 16) ^ ((row_ & 7) << 4));\
            *(bf16x8*)((char*)KsL[bu] + byte_) = nk[i_];                          \
            *(bf16x8*)((char*)VtL[bu] + byte_) = nv[i_];                          \
        }                                                                         \
    } while (0)

    LOADN(0);
    WRITEN(0);
    __syncthreads();

    int cbuf = 0;
    for (int ct = 0; ct < S_ / 64; ct++) {
        if (ct + 1 < S_ / 64) LOADN(ct + 1);   // issue early: hide under compute

        // ---- S^T = mfma(K, Q): lane holds 16 vals of q-row (w*16+l16) ----
        f32x4 sacc[4];
        __builtin_amdgcn_s_setprio(1);
        #pragma unroll
        for (int n = 0; n < 4; n++) {
            sacc[n][0] = sacc[n][1] = sacc[n][2] = sacc[n][3] = 0.f;
            bf16x8 kb0 = *LDSRD(KsL[cbuf], n * 16 + l16, lg * 16);
            bf16x8 kb1 = *LDSRD(KsL[cbuf], n * 16 + l16, 64 + lg * 16);
            sacc[n] = __builtin_amdgcn_mfma_f32_16x16x32_bf16(kb0, qf0, sacc[n], 0, 0, 0);
            sacc[n] = __builtin_amdgcn_mfma_f32_16x16x32_bf16(kb1, qf1, sacc[n], 0, 0, 0);
        }
        __builtin_amdgcn_s_setprio(0);

        // ---- mask (log2-scaled; per kc = 16n+4lg+r) ----
        #pragma unroll
        for (int n = 0; n < 4; n++) {
            float4 mk = *(const float4*)(mask + (size_t)b * S_ + ct * 64 + n * 16 + lg * 4);
            sacc[n][0] += mk.x; sacc[n][1] += mk.y; sacc[n][2] += mk.z; sacc[n][3] += mk.w;
        }

        // ---- softmax + P store (per-wave rows of PsL; no barrier) ----
        const int prow = w * 16 + l16;
        softmax_store(sacc, m_reg, l_reg, oacc, PsL, prow, lg);

        // ---- O += P V ----
        bf16x8 pa0 = *LDSRD(PsL, prow, lg * 16);
        bf16x8 pa1 = *LDSRD(PsL, prow, 64 + lg * 16);
        __builtin_amdgcn_s_setprio(1);
        #pragma unroll
        for (int nd = 0; nd < 4; nd++) {
            bf16x8 vb0 = *LDSRD(VtL[cbuf], nd * 16 + l16, lg * 16);
            bf16x8 vb1 = *LDSRD(VtL[cbuf], nd * 16 + l16, 64 + lg * 16);
            oacc[nd] = __builtin_amdgcn_mfma_f32_16x16x32_bf16(pa0, vb0, oacc[nd], 0, 0, 0);
            oacc[nd] = __builtin_amdgcn_mfma_f32_16x16x32_bf16(pa1, vb1, oacc[nd], 0, 0, 0);
        }
        __builtin_amdgcn_s_setprio(0);

        // ---- write-late: staged regs -> other buffer (waits vmcnt inside) ----
        if (ct + 1 < S_ / 64) WRITEN(cbuf ^ 1);
        __syncthreads();   // publish next buffer / protect P+V reads
        cbuf ^= 1;
    }
    #undef LOADN
    #undef WRITEN

    // ---- normalize + write ctx bf16 [M][H] ----
    #pragma unroll
    for (int r = 0; r < 4; r++) {
        const float inv = 1.f / __shfl(l_reg, lg * 4 + r);
        const size_t row = (size_t)(b * S_ + qt * 64 + w * 16 + lg * 4 + r);
        #pragma unroll
        for (int nd = 0; nd < 4; nd++)
            ctx[row * H_ + h * HD_ + nd * 16 + l16] = f2bf(oacc[nd][r] * inv);
    }
}

// ---------------------------------------------------------------------------
// LayerNorm over last dim (768). One block (256 thr) per row.
// ---------------------------------------------------------------------------
__global__ __launch_bounds__(256)
void layernorm_k(const float* __restrict__ hin, const float* __restrict__ g,
                 const float* __restrict__ beta, float* __restrict__ out) {
    const int row = blockIdx.x;
    const int tid = threadIdx.x;
    const float* x = hin + (size_t)row * H_;
    __shared__ float sm[4];

    float v0 = x[tid], v1 = x[tid + 256], v2 = x[tid + 512];
    float s = v0 + v1 + v2;
    #pragma unroll
    for (int o = 32; o > 0; o >>= 1) s += __shfl_xor(s, o);
    if ((tid & 63) == 0) sm[tid >> 6] = s;
    __syncthreads();
    float mu = (sm[0] + sm[1] + sm[2] + sm[3]) * (1.f / 768.f);

    float d0 = v0 - mu, d1 = v1 - mu, d2 = v2 - mu;
    float ss = d0*d0 + d1*d1 + d2*d2;
    #pragma unroll
    for (int o = 32; o > 0; o >>= 1) ss += __shfl_xor(ss, o);
    __syncthreads();
    if ((tid & 63) == 0) sm[tid >> 6] = ss;
    __syncthreads();
    float var = (sm[0] + sm[1] + sm[2] + sm[3]) * (1.f / 768.f);
    float sc = rsqrtf(var + 1e-12f);

    float* y = out + (size_t)row * H_;
    y[tid]       = d0 * sc * g[tid]       + beta[tid];
    y[tid + 256] = d1 * sc * g[tid + 256] + beta[tid + 256];
    y[tid + 512] = d2 * sc * g[tid + 512] + beta[tid + 512];
}

// ---------------------------------------------------------------------------
extern "C" void kernel_launch(void* const* d_in, const int* in_sizes, int n_in,
                              void* d_out, int out_size, void* d_ws, size_t ws_size,
                              hipStream_t stream) {
    const float* hs   = (const float*)d_in[0];
    const float* mask = (const float*)d_in[1];
    const float* Wq   = (const float*)d_in[2];
    const float* bq   = (const float*)d_in[3];
    const float* Wk   = (const float*)d_in[4];
    const float* bk   = (const float*)d_in[5];
    const float* Wv   = (const float*)d_in[6];
    const float* bv   = (const float*)d_in[7];
    const float* Wo   = (const float*)d_in[8];
    const float* bo   = (const float*)d_in[9];
    const float* ln_g = (const float*)d_in[10];
    const float* ln_b = (const float*)d_in[11];
    float* out = (float*)d_out;

    const size_t MH = (size_t)M_ * H_;
    const size_t HH = (size_t)H_ * H_;
    short* hsbf = (short*)d_ws;       // [M][768] bf16
    short* wqbf = hsbf + MH;          // [2304][768] consecutive Wq,Wk,Wv
    short* wkbf = wqbf + HH;
    short* wvbf = wkbf + HH;
    short* wobf = wvbf + HH;
    short* qbf  = wobf + HH;          // [b][h][s][d] bf16; q,k,v consecutive
    short* kbf  = qbf + MH;
    short* vbf  = kbf + MH;           // [b][h][s][d]
    short* vtb  = vbf + MH;           // [b][h][d][s]
    short* cbf  = vtb + MH;           // ctx bf16 [M][768]
    float* hb   = (float*)(cbf + MH); // fp32 [M][768]
    float* msk2 = hb + MH;            // mask * log2e (8192 fp32)

    cvt5<<<dim3(256, 5), 256, 0, stream>>>(hs, Wq, Wk, Wv, Wo,
                                           hsbf, wqbf, wkbf, wvbf, wobf);
    scale_mask<<<(B_ * S_ + 255) / 256, 256, 0, stream>>>(mask, msk2);

    gemm_qkv<<<dim3(M_ / 128, 18), 256, 0, stream>>>(hsbf, wqbf, bq, bk, bv, qbf);

    transpose_v<<<dim3(S_ / 64, B_ * NH_), 256, 0, stream>>>(vbf, vtb);

    flash_attn_mfma<<<dim3(S_ / 64, NH_, B_), 256, 0, stream>>>(qbf, kbf, vtb, msk2, cbf);

    gemm_out<<<dim3(M_ / 128, H_ / 128), 256, 0, stream>>>(cbf, wobf, bo, hs, hb);

    layernorm_k<<<M_, 256, 0, stream>>>(hb, ln_g, ln_b, out);
}

// Round 9
// 194.747 us; speedup vs baseline: 1.2997x; 1.0391x over previous
//
#include <hip/hip_runtime.h>
#include <math.h>

#define B_  4
#define S_  2048
#define H_  768
#define NH_ 12
#define HD_ 64
#define M_  (B_*S_)   // 8192
#define K_  768
#define LOG2E 1.44269504088896340736f

using bf16x8 = __attribute__((ext_vector_type(8))) short;
using s16x4  = __attribute__((ext_vector_type(4))) short;
using f32x4  = __attribute__((ext_vector_type(4))) float;

__device__ inline short f2bf(float f) {
    union { float f; unsigned u; } v{f};
    unsigned r = (v.u + 0x7FFF + ((v.u >> 16) & 1)) >> 16;   // RNE
    return (short)r;
}

__device__ inline unsigned cvt_pk_bf16(float lo, float hi) {
    unsigned r;
    asm("v_cvt_pk_bf16_f32 %0, %1, %2" : "=v"(r) : "v"(lo), "v"(hi));
    return r;
}

#define GLDS16(g, l) __builtin_amdgcn_global_load_lds( \
    (const __attribute__((address_space(1))) void*)(g), \
    (__attribute__((address_space(3))) void*)(l), 16, 0, 0)

// swizzled LDS read: linear [R][128B] tile, byte ^= ((row&7)<<4)
__device__ inline const bf16x8* LDSRD(const short* base, int row, int colByte) {
    return (const bf16x8*)((const char*)base + ((row << 7) + (colByte ^ ((row & 7) << 4))));
}

// ---------------------------------------------------------------------------
// fp32 -> bf16 conversion: region per blockIdx.y (hs, Wq, Wk, Wv, Wo)
// ---------------------------------------------------------------------------
__global__ __launch_bounds__(256)
void cvt5(const float* __restrict__ s0, const float* __restrict__ s1,
          const float* __restrict__ s2, const float* __restrict__ s3,
          const float* __restrict__ s4,
          short* __restrict__ d0, short* __restrict__ d1,
          short* __restrict__ d2, short* __restrict__ d3,
          short* __restrict__ d4) {
    const int r = blockIdx.y;
    const float* s = r == 0 ? s0 : r == 1 ? s1 : r == 2 ? s2 : r == 3 ? s3 : s4;
    short* d      = r == 0 ? d0 : r == 1 ? d1 : r == 2 ? d2 : r == 3 ? d3 : d4;
    const int n4  = (r == 0 ? M_ * H_ : H_ * H_) >> 2;
    for (int i = blockIdx.x * blockDim.x + threadIdx.x; i < n4; i += gridDim.x * blockDim.x) {
        float4 v = ((const float4*)s)[i];
        s16x4 o;
        o[0] = f2bf(v.x); o[1] = f2bf(v.y); o[2] = f2bf(v.z); o[3] = f2bf(v.w);
        ((s16x4*)d)[i] = o;
    }
}

// mask * log2e (fp32, tiny)
__global__ __launch_bounds__(256)
void scale_mask(const float* __restrict__ m, float* __restrict__ o) {
    const int i = blockIdx.x * 256 + threadIdx.x;
    if (i < B_ * S_) o[i] = m[i] * LOG2E;
}

// ---------------------------------------------------------------------------
// Fused QKV GEMM: weights stored consecutively as [2304][768] bf16.
// grid (M/128, 18). which = y/6 (0=Q,1=K,2=V); out bf16 head-major.
// ---------------------------------------------------------------------------
__global__ __launch_bounds__(256)
void gemm_qkv(const short* __restrict__ A, const short* __restrict__ Bw,
              const float* __restrict__ bq, const float* __restrict__ bk,
              const float* __restrict__ bv, short* __restrict__ obase) {
    __shared__ __align__(16) short As[128 * 32];
    __shared__ __align__(16) short Bs[128 * 32];
    const int tid = threadIdx.x;
    const int w = tid >> 6, l = tid & 63;
    const int l16 = l & 15, lg = l >> 4;
    const int wm = w >> 1, wn = w & 1;
    const int m0 = blockIdx.x * 128, n0 = blockIdx.y * 128;
    const int which = blockIdx.y / 6;
    const float* bias = which == 0 ? bq : which == 1 ? bk : bv;
    const float scale = which == 0 ? 0.125f * LOG2E : 1.0f;
    short* obf = obase + (size_t)which * M_ * H_;

    f32x4 acc[4][4];
    #pragma unroll
    for (int mi = 0; mi < 4; mi++)
        #pragma unroll
        for (int ni = 0; ni < 4; ni++)
            acc[mi][ni][0] = acc[mi][ni][1] = acc[mi][ni][2] = acc[mi][ni][3] = 0.f;

    for (int k0 = 0; k0 < K_; k0 += 32) {
        #pragma unroll
        for (int i = 0; i < 2; i++) {
            const int o = w * 2048 + i * 1024 + l * 16;
            const int row = o >> 6, colb = o & 63;
            const char* ga = (const char*)A  + (((size_t)(m0 + row)) * K_ + k0) * 2 + colb;
            const char* gb = (const char*)Bw + (((size_t)(n0 + row)) * K_ + k0) * 2 + colb;
            GLDS16(ga, (char*)As + w * 2048 + i * 1024);
            GLDS16(gb, (char*)Bs + w * 2048 + i * 1024);
        }
        __syncthreads();

        bf16x8 af[4], bfr[4];
        #pragma unroll
        for (int mi = 0; mi < 4; mi++)
            af[mi] = *(const bf16x8*)&As[(wm * 64 + mi * 16 + l16) * 32 + lg * 8];
        #pragma unroll
        for (int ni = 0; ni < 4; ni++)
            bfr[ni] = *(const bf16x8*)&Bs[(wn * 64 + ni * 16 + l16) * 32 + lg * 8];
        #pragma unroll
        for (int mi = 0; mi < 4; mi++)
            #pragma unroll
            for (int ni = 0; ni < 4; ni++)
                acc[mi][ni] = __builtin_amdgcn_mfma_f32_16x16x32_bf16(af[mi], bfr[ni], acc[mi][ni], 0, 0, 0);
        __syncthreads();
    }

    const int ncol0 = (blockIdx.y % 6) * 128;
    float bcol[4];
    #pragma unroll
    for (int ni = 0; ni < 4; ni++) bcol[ni] = bias[ncol0 + wn * 64 + ni * 16 + l16];

    const int h = (blockIdx.y % 6) * 2 + wn;
    #pragma unroll
    for (int mi = 0; mi < 4; mi++) {
        #pragma unroll
        for (int r = 0; r < 4; r++) {
            const int row = m0 + wm * 64 + mi * 16 + lg * 4 + r;
            const int bb = row >> 11, ss = row & 2047;
            const size_t base = (((size_t)(bb * NH_ + h)) * S_ + ss) * HD_;
            #pragma unroll
            for (int ni = 0; ni < 4; ni++)
                obf[base + ni * 16 + l16] = f2bf((acc[mi][ni][r] + bcol[ni]) * scale);
        }
    }
}

// ---------------------------------------------------------------------------
// O-proj GEMM: out fp32 = acc + bias + res  (128x128, BK=32, global_load_lds)
// ---------------------------------------------------------------------------
__global__ __launch_bounds__(256)
void gemm_out(const short* __restrict__ A, const short* __restrict__ Bw,
              const float* __restrict__ bias, const float* __restrict__ res,
              float* __restrict__ o) {
    __shared__ __align__(16) short As[128 * 32];
    __shared__ __align__(16) short Bs[128 * 32];
    const int tid = threadIdx.x;
    const int w = tid >> 6, l = tid & 63;
    const int l16 = l & 15, lg = l >> 4;
    const int wm = w >> 1, wn = w & 1;
    const int m0 = blockIdx.x * 128, n0 = blockIdx.y * 128;

    f32x4 acc[4][4];
    #pragma unroll
    for (int mi = 0; mi < 4; mi++)
        #pragma unroll
        for (int ni = 0; ni < 4; ni++)
            acc[mi][ni][0] = acc[mi][ni][1] = acc[mi][ni][2] = acc[mi][ni][3] = 0.f;

    for (int k0 = 0; k0 < K_; k0 += 32) {
        #pragma unroll
        for (int i = 0; i < 2; i++) {
            const int o_ = w * 2048 + i * 1024 + l * 16;
            const int row = o_ >> 6, colb = o_ & 63;
            const char* ga = (const char*)A  + (((size_t)(m0 + row)) * K_ + k0) * 2 + colb;
            const char* gb = (const char*)Bw + (((size_t)(n0 + row)) * K_ + k0) * 2 + colb;
            GLDS16(ga, (char*)As + w * 2048 + i * 1024);
            GLDS16(gb, (char*)Bs + w * 2048 + i * 1024);
        }
        __syncthreads();

        bf16x8 af[4], bfr[4];
        #pragma unroll
        for (int mi = 0; mi < 4; mi++)
            af[mi] = *(const bf16x8*)&As[(wm * 64 + mi * 16 + l16) * 32 + lg * 8];
        #pragma unroll
        for (int ni = 0; ni < 4; ni++)
            bfr[ni] = *(const bf16x8*)&Bs[(wn * 64 + ni * 16 + l16) * 32 + lg * 8];
        #pragma unroll
        for (int mi = 0; mi < 4; mi++)
            #pragma unroll
            for (int ni = 0; ni < 4; ni++)
                acc[mi][ni] = __builtin_amdgcn_mfma_f32_16x16x32_bf16(af[mi], bfr[ni], acc[mi][ni], 0, 0, 0);
        __syncthreads();
    }

    float bcol[4];
    #pragma unroll
    for (int ni = 0; ni < 4; ni++) bcol[ni] = bias[n0 + wn * 64 + ni * 16 + l16];
    #pragma unroll
    for (int mi = 0; mi < 4; mi++) {
        #pragma unroll
        for (int r = 0; r < 4; r++) {
            const int row = m0 + wm * 64 + mi * 16 + lg * 4 + r;
            #pragma unroll
            for (int ni = 0; ni < 4; ni++) {
                const int col = n0 + wn * 64 + ni * 16 + l16;
                o[(size_t)row * H_ + col] = acc[mi][ni][r] + bcol[ni] + res[(size_t)row * H_ + col];
            }
        }
    }
}

// ---------------------------------------------------------------------------
// V transpose: [b][h][s][d] -> [b][h][d][s].  64x64 LDS tiles, XOR-swizzled.
// ---------------------------------------------------------------------------
__global__ __launch_bounds__(256)
void transpose_v(const short* __restrict__ vin, short* __restrict__ vout) {
    __shared__ __align__(16) short L[4096];
    const int bh = blockIdx.y, st = blockIdx.x * 64;
    const int t = threadIdx.x;
    const int sl = t >> 2, d0 = (t & 3) * 16;
    const short* g = vin + ((size_t)bh * S_ + st + sl) * HD_ + d0;
    #pragma unroll
    for (int u = 0; u < 2; u++) {
        const int cb = (d0 + u * 8) * 2;
        *(bf16x8*)((char*)L + (sl << 7) + (cb ^ ((sl & 7) << 4))) = *(const bf16x8*)(g + u * 8);
    }
    __syncthreads();
    const int d = t >> 2, s0 = (t & 3) * 16;
    short tmp[16];
    #pragma unroll
    for (int j = 0; j < 16; j++) {
        const int row = s0 + j;
        tmp[j] = *(const short*)((const char*)L + (row << 7) + ((d * 2) ^ ((row & 7) << 4)));
    }
    short* o = vout + ((size_t)bh * HD_ + d) * S_ + st + s0;
    *(bf16x8*)(o)     = *(bf16x8*)&tmp[0];
    *(bf16x8*)(o + 8) = *(bf16x8*)&tmp[8];
}

// ---------------------------------------------------------------------------
// MFMA flash attention: Q-block 64 (4 waves x 16 q-rows), KV tile 64.
// T14 async-STAGE split, one barrier/tile.  exp2 softmax with:
//   - mask folded into QK^T MFMA C-init (no VALU adds)
//   - row-sum l accumulated by ones-MFMA in O-layout (no VALU reduce)
//   - defer-max (T13), cvt_pk P-pack (T12 primitive)
// Q pre-scaled 0.125*log2e; mask pre-scaled log2e.
// ---------------------------------------------------------------------------
__global__ __launch_bounds__(256)
void flash_attn_mfma(const short* __restrict__ q, const short* __restrict__ k,
                     const short* __restrict__ vt, const float* __restrict__ mask,
                     short* __restrict__ ctx) {
    const int qt = blockIdx.x, h = blockIdx.y, b = blockIdx.z;
    __shared__ __align__(16) short KsL[2][4096];   // [buf][64 s][128B] swz
    __shared__ __align__(16) short VtL[2][4096];   // [buf][64 d][128B] swz
    __shared__ __align__(16) short PsL[4096];      // [64 q-rows][128B] swz
    const int tid = threadIdx.x;
    const int w = tid >> 6, l = tid & 63;
    const int l16 = l & 15, lg = l >> 4;

    const size_t bh = (size_t)(b * NH_ + h);
    const size_t qrow = (bh * S_ + qt * 64 + w * 16 + l16) * HD_;
    bf16x8 qf0 = *(const bf16x8*)(q + qrow + lg * 8);
    bf16x8 qf1 = *(const bf16x8*)(q + qrow + 32 + lg * 8);

    const size_t kbase  = bh * S_ * HD_;   // K  [s][d]
    const size_t vtbase = bh * HD_ * S_;   // Vt [d][s]

    // ones B-fragment for row-sum MFMA (bf16 1.0 = 0x3F80)
    bf16x8 ones;
    #pragma unroll
    for (int j = 0; j < 8; j++) ones[j] = (short)0x3F80;

    f32x4 oacc[4], lsum;
    #pragma unroll
    for (int i = 0; i < 4; i++) oacc[i][0] = oacc[i][1] = oacc[i][2] = oacc[i][3] = 0.f;
    lsum[0] = lsum[1] = lsum[2] = lsum[3] = 0.f;
    float m_reg = -3.0e38f;

    // staging regs: wave w stages rows w*16..w*16+15 of K tile and of Vt tile
    bf16x8 nk[2], nv[2];
    #define LOADN(ct_) do {                                                       \
        _Pragma("unroll")                                                         \
        for (int i_ = 0; i_ < 2; i_++) {                                          \
            const int c_ = l * 2 + i_;                                            \
            const int row_ = w * 16 + (c_ >> 3);                                  \
            const int cB_ = (c_ & 7) * 16;                                        \
            nk[i_] = *(const bf16x8*)((const char*)(k  + kbase  + (size_t)((ct_) * 64 + row_) * HD_) + cB_); \
            nv[i_] = *(const bf16x8*)((const char*)(vt + vtbase + (size_t)row_ * S_ + (ct_) * 64) + cB_);    \
        }                                                                         \
    } while (0)
    #define WRITEN(bu) do {                                                       \
        _Pragma("unroll")                                                         \
        for (int i_ = 0; i_ < 2; i_++) {                                          \
            const int c_ = l * 2 + i_;                                            \
            const int row_ = w * 16 + (c_ >> 3);                                  \
            const int byte_ = (row_ << 7) + (((c_ & 7) * 16) ^ ((row_ & 7) << 4));\
            *(bf16x8*)((char*)KsL[bu] + byte_) = nk[i_];                          \
            *(bf16x8*)((char*)VtL[bu] + byte_) = nv[i_];                          \
        }                                                                         \
    } while (0)

    LOADN(0);
    WRITEN(0);
    __syncthreads();

    int cbuf = 0;
    for (int ct = 0; ct < S_ / 64; ct++) {
        if (ct + 1 < S_ / 64) LOADN(ct + 1);   // issue early: hide under compute

        // ---- S^T = mfma(K, Q) with C initialized to the (log2-scaled) mask ----
        f32x4 sacc[4];
        #pragma unroll
        for (int n = 0; n < 4; n++) {
            float4 mk = *(const float4*)(mask + (size_t)b * S_ + ct * 64 + n * 16 + lg * 4);
            sacc[n][0] = mk.x; sacc[n][1] = mk.y; sacc[n][2] = mk.z; sacc[n][3] = mk.w;
        }
        __builtin_amdgcn_s_setprio(1);
        #pragma unroll
        for (int n = 0; n < 4; n++) {
            bf16x8 kb0 = *LDSRD(KsL[cbuf], n * 16 + l16, lg * 16);
            bf16x8 kb1 = *LDSRD(KsL[cbuf], n * 16 + l16, 64 + lg * 16);
            sacc[n] = __builtin_amdgcn_mfma_f32_16x16x32_bf16(kb0, qf0, sacc[n], 0, 0, 0);
            sacc[n] = __builtin_amdgcn_mfma_f32_16x16x32_bf16(kb1, qf1, sacc[n], 0, 0, 0);
        }
        __builtin_amdgcn_s_setprio(0);

        // ---- lane-local max for q-row l16 (tree; fuses to v_max3) ----
        float x0 = fmaxf(fmaxf(sacc[0][0], sacc[0][1]), fmaxf(sacc[0][2], sacc[0][3]));
        float x1 = fmaxf(fmaxf(sacc[1][0], sacc[1][1]), fmaxf(sacc[1][2], sacc[1][3]));
        float x2 = fmaxf(fmaxf(sacc[2][0], sacc[2][1]), fmaxf(sacc[2][2], sacc[2][3]));
        float x3 = fmaxf(fmaxf(sacc[3][0], sacc[3][1]), fmaxf(sacc[3][2], sacc[3][3]));
        float pmax = fmaxf(fmaxf(x0, x1), fmaxf(x2, x3));
        pmax = fmaxf(pmax, __shfl_xor(pmax, 16));
        pmax = fmaxf(pmax, __shfl_xor(pmax, 32));

        // ---- defer-max rescale (T13); corr redistributed to O-layout ----
        if (!__all(pmax - m_reg <= 8.f)) {
            const float mn = fmaxf(m_reg, pmax);
            const float corr = __builtin_amdgcn_exp2f(m_reg - mn);
            m_reg = mn;
            float corr4[4];
            #pragma unroll
            for (int r = 0; r < 4; r++) corr4[r] = __shfl(corr, lg * 4 + r);
            #pragma unroll
            for (int nd = 0; nd < 4; nd++)
                #pragma unroll
                for (int r = 0; r < 4; r++) oacc[nd][r] *= corr4[r];
            #pragma unroll
            for (int r = 0; r < 4; r++) lsum[r] *= corr4[r];
        }

        // ---- P = exp2(s - m); pack to LDS via v_cvt_pk_bf16_f32 ----
        const int prow = w * 16 + l16;
        #pragma unroll
        for (int n = 0; n < 4; n++) {
            uint2 pk;
            pk.x = cvt_pk_bf16(__builtin_amdgcn_exp2f(sacc[n][0] - m_reg),
                               __builtin_amdgcn_exp2f(sacc[n][1] - m_reg));
            pk.y = cvt_pk_bf16(__builtin_amdgcn_exp2f(sacc[n][2] - m_reg),
                               __builtin_amdgcn_exp2f(sacc[n][3] - m_reg));
            *(uint2*)((char*)PsL + (prow << 7) + ((32 * n + 8 * lg) ^ ((prow & 7) << 4))) = pk;
        }

        // ---- O += P V ; l += P 1  (row-sum via ones-MFMA, lands in O-layout) ----
        bf16x8 pa0 = *LDSRD(PsL, prow, lg * 16);
        bf16x8 pa1 = *LDSRD(PsL, prow, 64 + lg * 16);
        __builtin_amdgcn_s_setprio(1);
        lsum = __builtin_amdgcn_mfma_f32_16x16x32_bf16(pa0, ones, lsum, 0, 0, 0);
        lsum = __builtin_amdgcn_mfma_f32_16x16x32_bf16(pa1, ones, lsum, 0, 0, 0);
        #pragma unroll
        for (int nd = 0; nd < 4; nd++) {
            bf16x8 vb0 = *LDSRD(VtL[cbuf], nd * 16 + l16, lg * 16);
            bf16x8 vb1 = *LDSRD(VtL[cbuf], nd * 16 + l16, 64 + lg * 16);
            oacc[nd] = __builtin_amdgcn_mfma_f32_16x16x32_bf16(pa0, vb0, oacc[nd], 0, 0, 0);
            oacc[nd] = __builtin_amdgcn_mfma_f32_16x16x32_bf16(pa1, vb1, oacc[nd], 0, 0, 0);
        }
        __builtin_amdgcn_s_setprio(0);

        // ---- write-late: staged regs -> other buffer ----
        if (ct + 1 < S_ / 64) WRITEN(cbuf ^ 1);
        __syncthreads();   // publish next buffer / protect P+V reads
        cbuf ^= 1;
    }
    #undef LOADN
    #undef WRITEN

    // ---- normalize + write ctx bf16 [M][H] (lsum already in O-layout) ----
    #pragma unroll
    for (int r = 0; r < 4; r++) {
        const float inv = 1.f / lsum[r];
        const size_t row = (size_t)(b * S_ + qt * 64 + w * 16 + lg * 4 + r);
        #pragma unroll
        for (int nd = 0; nd < 4; nd++)
            ctx[row * H_ + h * HD_ + nd * 16 + l16] = f2bf(oacc[nd][r] * inv);
    }
}

// ---------------------------------------------------------------------------
// LayerNorm over last dim (768). One block (256 thr) per row.
// ---------------------------------------------------------------------------
__global__ __launch_bounds__(256)
void layernorm_k(const float* __restrict__ hin, const float* __restrict__ g,
                 const float* __restrict__ beta, float* __restrict__ out) {
    const int row = blockIdx.x;
    const int tid = threadIdx.x;
    const float* x = hin + (size_t)row * H_;
    __shared__ float sm[4];

    float v0 = x[tid], v1 = x[tid + 256], v2 = x[tid + 512];
    float s = v0 + v1 + v2;
    #pragma unroll
    for (int o = 32; o > 0; o >>= 1) s += __shfl_xor(s, o);
    if ((tid & 63) == 0) sm[tid >> 6] = s;
    __syncthreads();
    float mu = (sm[0] + sm[1] + sm[2] + sm[3]) * (1.f / 768.f);

    float d0 = v0 - mu, d1 = v1 - mu, d2 = v2 - mu;
    float ss = d0*d0 + d1*d1 + d2*d2;
    #pragma unroll
    for (int o = 32; o > 0; o >>= 1) ss += __shfl_xor(ss, o);
    __syncthreads();
    if ((tid & 63) == 0) sm[tid >> 6] = ss;
    __syncthreads();
    float var = (sm[0] + sm[1] + sm[2] + sm[3]) * (1.f / 768.f);
    float sc = rsqrtf(var + 1e-12f);

    float* y = out + (size_t)row * H_;
    y[tid]       = d0 * sc * g[tid]       + beta[tid];
    y[tid + 256] = d1 * sc * g[tid + 256] + beta[tid + 256];
    y[tid + 512] = d2 * sc * g[tid + 512] + beta[tid + 512];
}

// ---------------------------------------------------------------------------
extern "C" void kernel_launch(void* const* d_in, const int* in_sizes, int n_in,
                              void* d_out, int out_size, void* d_ws, size_t ws_size,
                              hipStream_t stream) {
    const float* hs   = (const float*)d_in[0];
    const float* mask = (const float*)d_in[1];
    const float* Wq   = (const float*)d_in[2];
    const float* bq   = (const float*)d_in[3];
    const float* Wk   = (const float*)d_in[4];
    const float* bk   = (const float*)d_in[5];
    const float* Wv   = (const float*)d_in[6];
    const float* bv   = (const float*)d_in[7];
    const float* Wo   = (const float*)d_in[8];
    const float* bo   = (const float*)d_in[9];
    const float* ln_g = (const float*)d_in[10];
    const float* ln_b = (const float*)d_in[11];
    float* out = (float*)d_out;

    const size_t MH = (size_t)M_ * H_;
    const size_t HH = (size_t)H_ * H_;
    short* hsbf = (short*)d_ws;       // [M][768] bf16
    short* wqbf = hsbf + MH;          // [2304][768] consecutive Wq,Wk,Wv
    short* wkbf = wqbf + HH;
    short* wvbf = wkbf + HH;
    short* wobf = wvbf + HH;
    short* qbf  = wobf + HH;          // [b][h][s][d] bf16; q,k,v consecutive
    short* kbf  = qbf + MH;
    short* vbf  = kbf + MH;           // [b][h][s][d]
    short* vtb  = vbf + MH;           // [b][h][d][s]
    short* cbf  = vtb + MH;           // ctx bf16 [M][768]
    float* hb   = (float*)(cbf + MH); // fp32 [M][768]
    float* msk2 = hb + MH;            // mask * log2e (8192 fp32)

    cvt5<<<dim3(256, 5), 256, 0, stream>>>(hs, Wq, Wk, Wv, Wo,
                                           hsbf, wqbf, wkbf, wvbf, wobf);
    scale_mask<<<(B_ * S_ + 255) / 256, 256, 0, stream>>>(mask, msk2);

    gemm_qkv<<<dim3(M_ / 128, 18), 256, 0, stream>>>(hsbf, wqbf, bq, bk, bv, qbf);

    transpose_v<<<dim3(S_ / 64, B_ * NH_), 256, 0, stream>>>(vbf, vtb);

    flash_attn_mfma<<<dim3(S_ / 64, NH_, B_), 256, 0, stream>>>(qbf, kbf, vtb, msk2, cbf);

    gemm_out<<<dim3(M_ / 128, H_ / 128), 256, 0, stream>>>(cbf, wobf, bo, hs, hb);

    layernorm_k<<<M_, 256, 0, stream>>>(hb, ln_g, ln_b, out);
}